// Round 9
// baseline (252.795 us; speedup 1.0000x reference)
//
#include <hip/hip_runtime.h>
#include <hip/hip_bf16.h>

// Capsule routing; u_hat never materialized. Per iter:
//   vjt: vj = S@W_o -> sumsq; t = W_o@vj (unnormalized, stored as bf16 hi/lo)
//   route: bb=(t.u^T)/nrm -> softmax_o -> Spart[nt] = Wv.u  (MFMA bf16)
// v6: all k_route operands pre-formatted in global (u_bf row-major bf16,
// uT_bf transposed bf16, t hi/lo bf16) -> phase1/phase2 are pure
// global-b128-load -> MFMA chains with ~3 barriers total (softmax only).

constexpr int B = 32, N = 1024, K = 512, O = 32, D = 64, F = 2048;
constexpr int NT = 32;  // n-tiles -> 32 partial-S slabs per b

typedef __attribute__((ext_vector_type(8))) short bf16x8;
typedef __attribute__((ext_vector_type(4))) float f32x4;

__device__ inline unsigned int pk_hi(float x, float y) {
  union { __hip_bfloat162 h; unsigned int u; } c;
  c.h = __float22bfloat162_rn(float2{x, y});
  return c.u;
}
__device__ inline unsigned short bf16_1(float x) {
  return (unsigned short)(pk_hi(x, 0.f) & 0xffffu);
}
__device__ inline void split2(float x, unsigned short& h, unsigned short& l) {
  h = bf16_1(x);
  l = bf16_1(x - __uint_as_float((unsigned int)h << 16));
}

// ---- prep: stream u once -> colsum, u_bf (row-major bf16), uT_bf (bf16 T) ----
// grid (B, N/32), 256 thr. LDS transpose tile 512k x 32n, stride 34 u16.
__global__ __launch_bounds__(256) void k_prep(const float* __restrict__ u,
                                              float* __restrict__ cs,
                                              unsigned short* __restrict__ u_bf,
                                              unsigned short* __restrict__ uT_bf) {
  __shared__ unsigned short uTl[512 * 34];  // 34816 B
  __shared__ float4 red[128];
  int b = blockIdx.x, n0 = blockIdx.y * 32;
  int tid = threadIdx.x;
  int kq = (tid & 127) * 4, ng = tid >> 7;
  const float* ub = u + ((size_t)b * N + n0 + ng * 16) * K + kq;
  float4 a = {0.f, 0.f, 0.f, 0.f};
#pragma unroll
  for (int nn = 0; nn < 16; nn++) {
    float4 v = *(const float4*)&ub[(size_t)nn * K];
    a.x += v.x; a.y += v.y; a.z += v.z; a.w += v.w;
    uint2 p;
    p.x = pk_hi(v.x, v.y);
    p.y = pk_hi(v.z, v.w);
    int n = ng * 16 + nn;
    *(uint2*)&u_bf[((size_t)b * N + n0 + n) * K + kq] = p;
    uTl[(kq + 0) * 34 + n] = (unsigned short)(p.x & 0xffff);
    uTl[(kq + 1) * 34 + n] = (unsigned short)(p.x >> 16);
    uTl[(kq + 2) * 34 + n] = (unsigned short)(p.y & 0xffff);
    uTl[(kq + 3) * 34 + n] = (unsigned short)(p.y >> 16);
  }
  if (ng) red[tid & 127] = a;
  __syncthreads();
  if (!ng) {
    float4 o = red[tid];
    atomicAdd(&cs[b * K + kq + 0], (a.x + o.x) * (1.f / 32.f));
    atomicAdd(&cs[b * K + kq + 1], (a.y + o.y) * (1.f / 32.f));
    atomicAdd(&cs[b * K + kq + 2], (a.z + o.z) * (1.f / 32.f));
    atomicAdd(&cs[b * K + kq + 3], (a.w + o.w) * (1.f / 32.f));
  }
  __syncthreads();
  // write uT_bf: 512 rows x 32 n (64B each) = 2048 x 16B chunks
#pragma unroll
  for (int h = 0; h < 8; h++) {
    int i = tid + h * 256;
    int k = i >> 2, c = i & 3;
    uint4 v;
    v.x = *(const unsigned int*)&uTl[k * 34 + 8 * c + 0];
    v.y = *(const unsigned int*)&uTl[k * 34 + 8 * c + 2];
    v.z = *(const unsigned int*)&uTl[k * 34 + 8 * c + 4];
    v.w = *(const unsigned int*)&uTl[k * 34 + 8 * c + 6];
    *(uint4*)&uT_bf[((size_t)b * K + k) * N + n0 + 8 * c] = v;
  }
}

// vj[d]=sum_k s[k]W[k,o*64+d] -> sumsq atomic; t = W_o@vj as bf16 hi/lo.
// slot 0: s = colsum row; else s = sum of 32 partial-S slabs.
__global__ __launch_bounds__(512) void k_vjt(const float* __restrict__ Sp,
                                             const float* __restrict__ colsum,
                                             const float* __restrict__ W,
                                             float* __restrict__ sumsq, int slot,
                                             unsigned short* __restrict__ t_hi,
                                             unsigned short* __restrict__ t_lo) {
  __shared__ __align__(16) float s_s[K];
  __shared__ float red[7][D];
  __shared__ __align__(16) float vs[D];
  int bo = blockIdx.x, b = bo >> 5, o = bo & 31;
  int d = threadIdx.x & 63, ks = threadIdx.x >> 6;
  if (slot == 0) {
    for (int i = threadIdx.x; i < K; i += 512) s_s[i] = colsum[(size_t)b * K + i];
  } else {
    const float* base = Sp + ((size_t)b * NT * O + o) * K;
    int i = threadIdx.x;
    float a = 0.f;
#pragma unroll
    for (int nt = 0; nt < NT; nt++) a += base[(size_t)nt * O * K + i];
    s_s[i] = a;
  }
  __syncthreads();
  float acc = 0.f;
  const float* Wc = W + (size_t)o * D + d;
  for (int k = ks * 64; k < ks * 64 + 64; k += 4) {
    acc += s_s[k] * Wc[(size_t)k * F] + s_s[k + 1] * Wc[(size_t)(k + 1) * F] +
           s_s[k + 2] * Wc[(size_t)(k + 2) * F] + s_s[k + 3] * Wc[(size_t)(k + 3) * F];
  }
  if (ks) red[ks - 1][d] = acc;
  __syncthreads();
  if (ks == 0) {
#pragma unroll
    for (int j = 0; j < 7; j++) acc += red[j][d];
    vs[d] = acc;
    float ss = acc * acc;
#pragma unroll
    for (int m = 32; m >= 1; m >>= 1) ss += __shfl_xor(ss, m, 64);
    if (d == 0) atomicAdd(&sumsq[slot], ss);
  }
  __syncthreads();
  {  // t phase: wave handles 64 rows, 8 lanes/row (coalesced)
    int wave = threadIdx.x >> 6, lane = threadIdx.x & 63;
    int rr = lane >> 3, dc = lane & 7;
    float4 va = *(const float4*)&vs[dc * 8];
    float4 vb = *(const float4*)&vs[dc * 8 + 4];
#pragma unroll
    for (int i = 0; i < 8; i++) {
      int kk = wave * 64 + i * 8 + rr;
      const float* Wr = W + (size_t)kk * F + o * 64 + dc * 8;
      float4 wa = *(const float4*)Wr;
      float4 wb = *(const float4*)(Wr + 4);
      float p = wa.x * va.x + wa.y * va.y + wa.z * va.z + wa.w * va.w +
                wb.x * vb.x + wb.y * vb.y + wb.z * vb.z + wb.w * vb.w;
      p += __shfl_xor(p, 1, 64);
      p += __shfl_xor(p, 2, 64);
      p += __shfl_xor(p, 4, 64);
      if (dc == 0) {
        unsigned short h, l;
        split2(p, h, l);
        t_hi[(size_t)bo * K + kk] = h;
        t_lo[(size_t)bo * K + kk] = l;
      }
    }
  }
}

// Final: vj from summed slabs -> squash -> out
__global__ __launch_bounds__(512) void k_out(const float* __restrict__ Sp,
                                             const float* __restrict__ W,
                                             float* __restrict__ out) {
  __shared__ __align__(16) float s_s[K];
  __shared__ float red[7][D];
  int bo = blockIdx.x, b = bo >> 5, o = bo & 31;
  int d = threadIdx.x & 63, ks = threadIdx.x >> 6;
  {
    const float* base = Sp + ((size_t)b * NT * O + o) * K;
    int i = threadIdx.x;
    float a = 0.f;
#pragma unroll
    for (int nt = 0; nt < NT; nt++) a += base[(size_t)nt * O * K + i];
    s_s[i] = a;
  }
  __syncthreads();
  float acc = 0.f;
  const float* Wc = W + (size_t)o * D + d;
  for (int k = ks * 64; k < ks * 64 + 64; k += 4) {
    acc += s_s[k] * Wc[(size_t)k * F] + s_s[k + 1] * Wc[(size_t)(k + 1) * F] +
           s_s[k + 2] * Wc[(size_t)(k + 2) * F] + s_s[k + 3] * Wc[(size_t)(k + 3) * F];
  }
  if (ks) red[ks - 1][d] = acc;
  __syncthreads();
  if (ks == 0) {
#pragma unroll
    for (int j = 0; j < 7; j++) acc += red[j][d];
    float ss = acc * acc;
#pragma unroll
    for (int m = 32; m >= 1; m >>= 1) ss += __shfl_xor(ss, m, 64);
    float s = ss + 1e-7f;
    out[(size_t)bo * D + d] = (sqrtf(s) / (0.5f + s)) * acc;
  }
}

// Fused routing step, 32-n tile, 256 thr (4 waves), grid (B,32).
// phase1: bb = t.u^T with A/B frags b128-loaded straight from global (L2-hot,
// no LDS, no barriers). softmax in LDS. phase2: Spart = Wv.u, B-frags b128
// from uT_bf. Plain stores (no atomics).
__global__ __launch_bounds__(256) void k_route(const unsigned short* __restrict__ t_hi,
                                               const unsigned short* __restrict__ t_lo,
                                               const unsigned short* __restrict__ u_bf,
                                               const unsigned short* __restrict__ uT_bf,
                                               const float* __restrict__ sumsq,
                                               int slot, float* __restrict__ Sp) {
  __shared__ float wv[32 * 36];
  __shared__ float psum[8 * 36];
  __shared__ float mbuf[36];
  __shared__ unsigned short wvh[32 * 40], wvl[32 * 40];

  const int b = blockIdx.x, n0 = blockIdx.y * 32;
  const int tid = threadIdx.x, lane = tid & 63, wave = tid >> 6;
  const int m = lane & 15, oct = lane >> 4;
  const float nrm_inv = rsqrtf(fmaxf(sumsq[slot], 1e-12f));

  // ---- phase 1: bb[32o][32n] = t . u^T (global frags, barrier-free) ----
  const int mo = wave & 1, nt = wave >> 1;
  const unsigned short* th = t_hi + ((size_t)b * O + mo * 16 + m) * K;
  const unsigned short* tl = t_lo + ((size_t)b * O + mo * 16 + m) * K;
  const unsigned short* ubf = u_bf + ((size_t)b * N + n0 + nt * 16 + m) * K;
  f32x4 accb = {0.f, 0.f, 0.f, 0.f};
#pragma unroll 4
  for (int kc = 0; kc < K; kc += 32) {
    int k0 = kc + oct * 8;
    bf16x8 ah = *(const bf16x8*)&th[k0];
    bf16x8 al = *(const bf16x8*)&tl[k0];
    bf16x8 bh = *(const bf16x8*)&ubf[k0];
    accb = __builtin_amdgcn_mfma_f32_16x16x32_bf16(ah, bh, accb, 0, 0, 0);
    accb = __builtin_amdgcn_mfma_f32_16x16x32_bf16(al, bh, accb, 0, 0, 0);
  }
#pragma unroll
  for (int r = 0; r < 4; r++)  // D: col=m (n), row=oct*4+r (o)
    wv[(mo * 16 + oct * 4 + r) * 36 + nt * 16 + m] = accb[r] * nrm_inv;
  __syncthreads();

  // ---- softmax over o, parallel: n=tid&31, g=tid>>5 owns 4 o's ----
  {
    int n = tid & 31, g = tid >> 5;
    float m4 = -1e30f;
#pragma unroll
    for (int j = 0; j < 4; j++) m4 = fmaxf(m4, wv[(g * 4 + j) * 36 + n]);
    psum[g * 36 + n] = m4;
    __syncthreads();
    if (tid < 32) {
      float mx = psum[tid];
#pragma unroll
      for (int gg = 1; gg < 8; gg++) mx = fmaxf(mx, psum[gg * 36 + tid]);
      mbuf[tid] = mx;
    }
    __syncthreads();
    float mx = mbuf[n];
    float s4 = 0.f;
#pragma unroll
    for (int j = 0; j < 4; j++) {
      float e = __expf(wv[(g * 4 + j) * 36 + n] - mx);
      wv[(g * 4 + j) * 36 + n] = e;
      s4 += e;
    }
    psum[g * 36 + n] = s4;
    __syncthreads();
    if (tid < 32) {
      float s = 0.f;
#pragma unroll
      for (int gg = 0; gg < 8; gg++) s += psum[gg * 36 + tid];
      mbuf[tid] = 1.f / s;
    }
    __syncthreads();
    float inv = mbuf[n];
#pragma unroll
    for (int j = 0; j < 4; j++) {
      unsigned short h, l;
      split2(wv[(g * 4 + j) * 36 + n] * inv, h, l);
      wvh[(g * 4 + j) * 40 + n] = h;
      wvl[(g * 4 + j) * 40 + n] = l;
    }
  }
  __syncthreads();

  // ---- phase 2: Spart = Wv . u (B-frags b128 from uT_bf, no staging) ----
  const int mo2 = wave & 1, kp = wave >> 1;
  const int o0 = mo2 * 16;
  bf16x8 a_h = *(const bf16x8*)&wvh[(o0 + m) * 40 + oct * 8];
  bf16x8 a_l = *(const bf16x8*)&wvl[(o0 + m) * 40 + oct * 8];
  const unsigned short* uTb = uT_bf + (size_t)b * K * N + n0;
  float* Sb = Sp + ((size_t)b * NT + blockIdx.y) * O * K;
#pragma unroll 4
  for (int it = 0; it < 16; it++) {
    int kcol = it * 32 + kp * 16 + m;
    bf16x8 bh = *(const bf16x8*)&uTb[(size_t)kcol * N + oct * 8];
    f32x4 acs = {0.f, 0.f, 0.f, 0.f};
    acs = __builtin_amdgcn_mfma_f32_16x16x32_bf16(a_h, bh, acs, 0, 0, 0);
    acs = __builtin_amdgcn_mfma_f32_16x16x32_bf16(a_l, bh, acs, 0, 0, 0);
#pragma unroll
    for (int r = 0; r < 4; r++)  // D: col=m -> kcol, row=oct*4+r -> o
      Sb[(size_t)(o0 + oct * 4 + r) * K + kcol] = acs[r];
  }
}

extern "C" void kernel_launch(void* const* d_in, const int* in_sizes, int n_in,
                              void* d_out, int out_size, void* d_ws, size_t ws_size,
                              hipStream_t stream) {
  const float* u = (const float*)d_in[0];  // [B,N,K] f32
  const float* W = (const float*)d_in[1];  // [K,F] f32
  float* out = (float*)d_out;              // [B,O,D] f32

  float* ws = (float*)d_ws;
  float* Sp = ws;                                        // B*NT*O*K fl (67MB)
  unsigned short* u_bf = (unsigned short*)(Sp + (size_t)B * NT * O * K);
  unsigned short* uT_bf = u_bf + (size_t)B * N * K;      // each 33.5MB
  unsigned short* t_hi = uT_bf + (size_t)B * N * K;      // B*O*K u16 (1MB)
  unsigned short* t_lo = t_hi + (size_t)B * O * K;
  float* colsum = (float*)(t_lo + (size_t)B * O * K);    // B*K
  float* sumsq = colsum + (size_t)B * K;                 // 16 (2 used)

  hipMemsetAsync(colsum, 0, ((size_t)B * K + 16) * sizeof(float), stream);

  k_prep<<<dim3(B, N / 32), 256, 0, stream>>>(u, colsum, u_bf, uT_bf);
  k_vjt<<<B * O, 512, 0, stream>>>(Sp, colsum, W, sumsq, 0, t_hi, t_lo);  // iter0
  k_route<<<dim3(B, NT), 256, 0, stream>>>(t_hi, t_lo, u_bf, uT_bf, sumsq, 0, Sp);
  k_vjt<<<B * O, 512, 0, stream>>>(Sp, colsum, W, sumsq, 1, t_hi, t_lo);  // iter1
  k_route<<<dim3(B, NT), 256, 0, stream>>>(t_hi, t_lo, u_bf, uT_bf, sumsq, 1, Sp);
  k_out<<<B * O, 512, 0, stream>>>(Sp, W, out);                           // iter2
}

// Round 11
// 201.454 us; speedup vs baseline: 1.2549x; 1.2549x over previous
//
#include <hip/hip_runtime.h>
#include <hip/hip_bf16.h>

// Capsule routing; u_hat never materialized. Per iter:
//   vjt: vj = S@W_o -> global sumsq; t = W_o@vj (UNNORMALIZED)
//   route: bb = (t.u^T)/nrm -> softmax_o -> Spart[nt] = Wv.u  (MFMA bf16 hi/lo)
// R8 structure (measured best, 215us) + bf16 partial-S slabs: halves the
// slab write traffic in k_route phase 2 and the slab-sum reads in vjt/out.

constexpr int B = 32, N = 1024, K = 512, O = 32, D = 64, F = 2048;
constexpr int NT = 32;   // n-tile -> 32 slabs per b
constexpr int ST = 72;   // LDS u16 row stride: 144B, 16B-aligned, b128-friendly

typedef __attribute__((ext_vector_type(8))) short bf16x8;
typedef __attribute__((ext_vector_type(4))) float f32x4;

__device__ inline unsigned int pk_hi(float x, float y) {
  union { __hip_bfloat162 h; unsigned int u; } c;
  c.h = __float22bfloat162_rn(float2{x, y});
  return c.u;
}
__device__ inline unsigned short bf16_1(float x) {
  return (unsigned short)(pk_hi(x, 0.f) & 0xffffu);
}
__device__ inline void split2(float x, unsigned short& h, unsigned short& l) {
  h = bf16_1(x);
  l = bf16_1(x - __uint_as_float((unsigned int)h << 16));
}
__device__ inline float bf2f(unsigned short h) {
  return __uint_as_float((unsigned int)h << 16);
}
__device__ inline int swz(int r) { return ((r >> 3) & 7) << 3; }

__device__ inline void stage_hi(unsigned short* hi, int r, int c4, float4 v) {
  int c = c4 ^ swz(r);
  uint2 p;
  p.x = pk_hi(v.x, v.y);
  p.y = pk_hi(v.z, v.w);
  *(uint2*)&hi[r * ST + c] = p;
}
__device__ inline void stage_hilo(unsigned short* hi, unsigned short* lo, int r,
                                  int c4, float4 v) {
  int c = c4 ^ swz(r);
  uint2 ph, pl;
  ph.x = pk_hi(v.x, v.y);
  ph.y = pk_hi(v.z, v.w);
  pl.x = pk_hi(v.x - __uint_as_float(ph.x << 16),
               v.y - __uint_as_float(ph.x & 0xffff0000u));
  pl.y = pk_hi(v.z - __uint_as_float(ph.y << 16),
               v.w - __uint_as_float(ph.y & 0xffff0000u));
  *(uint2*)&hi[r * ST + c] = ph;
  *(uint2*)&lo[r * ST + c] = pl;
}
__device__ inline bf16x8 frag_row(const unsigned short* p, int r, int k0) {
  return *(const bf16x8*)&p[r * ST + (k0 ^ swz(r))];
}
__device__ inline bf16x8 frag_col(const unsigned short* p, int c, int n0) {
  bf16x8 f;
#pragma unroll
  for (int j = 0; j < 8; j++) {
    int n = n0 + j;
    f[j] = (short)p[n * ST + (c ^ swz(n))];
  }
  return f;
}

// colsum[b,k] = (1/32) sum_n u[b,n,k]  (iter-0: softmax(0) uniform)
__global__ __launch_bounds__(256) void k_colsum(const float* __restrict__ u,
                                                float* __restrict__ cs) {
  int b = blockIdx.x, n0 = blockIdx.y * 32;
  int kq = (threadIdx.x & 127) * 4, ng = threadIdx.x >> 7;
  const float* ub = u + ((size_t)b * N + n0 + ng * 16) * K + kq;
  float4 a = {0.f, 0.f, 0.f, 0.f};
#pragma unroll
  for (int r = 0; r < 16; r++) {
    float4 v = *(const float4*)&ub[(size_t)r * K];
    a.x += v.x; a.y += v.y; a.z += v.z; a.w += v.w;
  }
  __shared__ float4 red[128];
  if (ng) red[threadIdx.x & 127] = a;
  __syncthreads();
  if (!ng) {
    float4 o = red[threadIdx.x];
    atomicAdd(&cs[b * K + kq + 0], (a.x + o.x) * (1.f / 32.f));
    atomicAdd(&cs[b * K + kq + 1], (a.y + o.y) * (1.f / 32.f));
    atomicAdd(&cs[b * K + kq + 2], (a.z + o.z) * (1.f / 32.f));
    atomicAdd(&cs[b * K + kq + 3], (a.w + o.w) * (1.f / 32.f));
  }
}

// vj[d]=sum_k s[k]W[k,o*64+d] -> sumsq atomic; t[k]=sum_d vj[d]W[k,o*64+d].
// slot 0: s = colsum row; else s = sum of 32 bf16 partial-S slabs.
__global__ __launch_bounds__(512) void k_vjt(const unsigned short* __restrict__ Sp,
                                             const float* __restrict__ colsum,
                                             const float* __restrict__ W,
                                             float* __restrict__ sumsq, int slot,
                                             float* __restrict__ t) {
  __shared__ __align__(16) float s_s[K];
  __shared__ float red[7][D];
  __shared__ __align__(16) float vs[D];
  int bo = blockIdx.x, b = bo >> 5, o = bo & 31;
  int d = threadIdx.x & 63, ks = threadIdx.x >> 6;  // 8-way k split
  if (slot == 0) {
    for (int i = threadIdx.x; i < K; i += 512) s_s[i] = colsum[(size_t)b * K + i];
  } else {
    const unsigned short* base = Sp + ((size_t)b * NT * O + o) * K;
    int i = threadIdx.x;  // 512 threads, one k each
    float a = 0.f;
#pragma unroll
    for (int nt = 0; nt < NT; nt++) a += bf2f(base[(size_t)nt * O * K + i]);
    s_s[i] = a;
  }
  __syncthreads();
  float acc = 0.f;
  const float* Wc = W + (size_t)o * D + d;
  for (int k = ks * 64; k < ks * 64 + 64; k += 4) {
    acc += s_s[k] * Wc[(size_t)k * F] + s_s[k + 1] * Wc[(size_t)(k + 1) * F] +
           s_s[k + 2] * Wc[(size_t)(k + 2) * F] + s_s[k + 3] * Wc[(size_t)(k + 3) * F];
  }
  if (ks) red[ks - 1][d] = acc;
  __syncthreads();
  if (ks == 0) {
#pragma unroll
    for (int j = 0; j < 7; j++) acc += red[j][d];
    vs[d] = acc;
    float ss = acc * acc;
#pragma unroll
    for (int m = 32; m >= 1; m >>= 1) ss += __shfl_xor(ss, m, 64);
    if (d == 0) atomicAdd(&sumsq[slot], ss);
  }
  __syncthreads();
  {  // t phase: wave handles 64 rows, 8 lanes/row (coalesced)
    int wave = threadIdx.x >> 6, lane = threadIdx.x & 63;
    int rr = lane >> 3, dc = lane & 7;
    float4 va = *(const float4*)&vs[dc * 8];
    float4 vb = *(const float4*)&vs[dc * 8 + 4];
#pragma unroll
    for (int i = 0; i < 8; i++) {
      int kk = wave * 64 + i * 8 + rr;
      const float* Wr = W + (size_t)kk * F + o * 64 + dc * 8;
      float4 wa = *(const float4*)Wr;
      float4 wb = *(const float4*)(Wr + 4);
      float p = wa.x * va.x + wa.y * va.y + wa.z * va.z + wa.w * va.w +
                wb.x * vb.x + wb.y * vb.y + wb.z * vb.z + wb.w * vb.w;
      p += __shfl_xor(p, 1, 64);
      p += __shfl_xor(p, 2, 64);
      p += __shfl_xor(p, 4, 64);
      if (dc == 0) t[(size_t)bo * K + kk] = p;
    }
  }
}

// Final: vj from summed bf16 slabs -> squash -> out
__global__ __launch_bounds__(512) void k_out(const unsigned short* __restrict__ Sp,
                                             const float* __restrict__ W,
                                             float* __restrict__ out) {
  __shared__ __align__(16) float s_s[K];
  __shared__ float red[7][D];
  int bo = blockIdx.x, b = bo >> 5, o = bo & 31;
  int d = threadIdx.x & 63, ks = threadIdx.x >> 6;
  {
    const unsigned short* base = Sp + ((size_t)b * NT * O + o) * K;
    int i = threadIdx.x;
    float a = 0.f;
#pragma unroll
    for (int nt = 0; nt < NT; nt++) a += bf2f(base[(size_t)nt * O * K + i]);
    s_s[i] = a;
  }
  __syncthreads();
  float acc = 0.f;
  const float* Wc = W + (size_t)o * D + d;
  for (int k = ks * 64; k < ks * 64 + 64; k += 4) {
    acc += s_s[k] * Wc[(size_t)k * F] + s_s[k + 1] * Wc[(size_t)(k + 1) * F] +
           s_s[k + 2] * Wc[(size_t)(k + 2) * F] + s_s[k + 3] * Wc[(size_t)(k + 3) * F];
  }
  if (ks) red[ks - 1][d] = acc;
  __syncthreads();
  if (ks == 0) {
#pragma unroll
    for (int j = 0; j < 7; j++) acc += red[j][d];
    float ss = acc * acc;
#pragma unroll
    for (int m = 32; m >= 1; m >>= 1) ss += __shfl_xor(ss, m, 64);
    float s = ss + 1e-7f;
    out[(size_t)bo * D + d] = (sqrtf(s) / (0.5f + s)) * acc;
  }
}

// Fused routing step, 32-n tile, 256 thr (4 waves), grid (B,32)=1024 blocks.
// phase1: bb[32o][32n]=(t.u^T)/nrm (per-chunk LDS staging, b128 frags);
// softmax over o (parallel); phase2: Spart[b,nt] = Wv.u (bf16 stores, no atomics)
__global__ __launch_bounds__(256, 4) void k_route(const float* __restrict__ t,
                                                  const float* __restrict__ u,
                                                  const float* __restrict__ sumsq,
                                                  int slot,
                                                  unsigned short* __restrict__ Sp) {
  __shared__ unsigned short u_hi[32 * ST];                   // 4608 B
  __shared__ unsigned short t_hi[32 * ST], t_lo[32 * ST];    // 2x4608 B
  __shared__ float wv[32 * 36];                              // 4608 B logits
  __shared__ float psum[8 * 36];                             // softmax partials
  __shared__ float mbuf[36];
  unsigned short* wvh = t_hi;  // alias: t dead after phase 1
  unsigned short* wvl = t_lo;

  const int b = blockIdx.x, n0 = blockIdx.y * 32;
  const int tid = threadIdx.x, lane = tid & 63, wave = tid >> 6;
  const int m = lane & 15, oct = lane >> 4;
  const float* ub = u + ((size_t)b * N + n0) * K;
  const float* tb = t + (size_t)b * O * K;
  const float nrm_inv = rsqrtf(fmaxf(sumsq[slot], 1e-12f));

  // ---- phase 1: bb[32o][32n] = t . u^T ----
  const int mo = wave & 1, nt = wave >> 1;  // o-half, n-half (16x16 tiles)
  f32x4 accb = {0.f, 0.f, 0.f, 0.f};
  for (int kc = 0; kc < K; kc += 64) {
    __syncthreads();
#pragma unroll
    for (int h = 0; h < 2; h++) {  // t: 512 f4 hi/lo + u: 512 f4 hi, 2+2/thread
      int i = tid + h * 256;
      int r = i >> 4, c4 = (i & 15) * 4;
      stage_hilo(t_hi, t_lo, r, c4, *(const float4*)&tb[(size_t)r * K + kc + c4]);
      stage_hi(u_hi, r, c4, *(const float4*)&ub[(size_t)r * K + kc + c4]);
    }
    __syncthreads();
#pragma unroll
    for (int ks = 0; ks < 64; ks += 32) {
      bf16x8 ah = frag_row(t_hi, mo * 16 + m, ks + oct * 8);
      bf16x8 al = frag_row(t_lo, mo * 16 + m, ks + oct * 8);
      bf16x8 bh = frag_row(u_hi, nt * 16 + m, ks + oct * 8);
      accb = __builtin_amdgcn_mfma_f32_16x16x32_bf16(ah, bh, accb, 0, 0, 0);
      accb = __builtin_amdgcn_mfma_f32_16x16x32_bf16(al, bh, accb, 0, 0, 0);
    }
  }
  __syncthreads();
#pragma unroll
  for (int r = 0; r < 4; r++)  // D: col=m (n), row=oct*4+r (o)
    wv[(mo * 16 + oct * 4 + r) * 36 + nt * 16 + m] = accb[r] * nrm_inv;
  __syncthreads();

  // ---- softmax over o, parallel: n=tid&31, g=tid>>5 owns 4 o's ----
  {
    int n = tid & 31, g = tid >> 5;
    float m4 = -1e30f;
#pragma unroll
    for (int j = 0; j < 4; j++) m4 = fmaxf(m4, wv[(g * 4 + j) * 36 + n]);
    psum[g * 36 + n] = m4;
    __syncthreads();
    if (tid < 32) {
      float mx = psum[tid];
#pragma unroll
      for (int gg = 1; gg < 8; gg++) mx = fmaxf(mx, psum[gg * 36 + tid]);
      mbuf[tid] = mx;
    }
    __syncthreads();
    float mx = mbuf[n];
    float s4 = 0.f;
#pragma unroll
    for (int j = 0; j < 4; j++) {
      float e = __expf(wv[(g * 4 + j) * 36 + n] - mx);
      wv[(g * 4 + j) * 36 + n] = e;
      s4 += e;
    }
    psum[g * 36 + n] = s4;
    __syncthreads();
    if (tid < 32) {
      float s = 0.f;
#pragma unroll
      for (int gg = 0; gg < 8; gg++) s += psum[gg * 36 + tid];
      mbuf[tid] = 1.f / s;
    }
    __syncthreads();
    float inv = mbuf[n];
#pragma unroll
    for (int j = 0; j < 4; j++) {  // Wv -> bf16 hi/lo into dead t region
      unsigned short h, l;
      split2(wv[(g * 4 + j) * 36 + n] * inv, h, l);
      wvh[(g * 4 + j) * ST + n] = h;
      wvl[(g * 4 + j) * ST + n] = l;
    }
  }
  __syncthreads();

  // ---- phase 2: Spart = Wv . u  (kred = n = 32, bf16 stores, no atomics) ----
  const int mo2 = wave & 1, kp = wave >> 1;  // o-half, ktile-pair
  const int o0 = mo2 * 16;
  bf16x8 a_h = *(const bf16x8*)&wvh[(o0 + m) * ST + oct * 8];
  bf16x8 a_l = *(const bf16x8*)&wvl[(o0 + m) * ST + oct * 8];
  unsigned short* Sb = Sp + ((size_t)b * NT + blockIdx.y) * O * K;
  for (int kc = 0; kc < K; kc += 64) {
    __syncthreads();
#pragma unroll
    for (int h = 0; h < 2; h++) {  // restage u chunk (L2/L3-hot), hi only
      int i = tid + h * 256;
      int r = i >> 4, c4 = (i & 15) * 4;
      stage_hi(u_hi, r, c4, *(const float4*)&ub[(size_t)r * K + kc + c4]);
    }
    __syncthreads();
#pragma unroll
    for (int kt = kp * 2; kt < kp * 2 + 2; kt++) {
      int c = kt * 16 + m;  // column within chunk
      bf16x8 bh = frag_col(u_hi, c, oct * 8);
      f32x4 acs = {0.f, 0.f, 0.f, 0.f};
      acs = __builtin_amdgcn_mfma_f32_16x16x32_bf16(a_h, bh, acs, 0, 0, 0);
      acs = __builtin_amdgcn_mfma_f32_16x16x32_bf16(a_l, bh, acs, 0, 0, 0);
#pragma unroll
      for (int r = 0; r < 4; r++)  // D: col=m -> kcol, row=oct*4+r -> o
        Sb[(size_t)(o0 + oct * 4 + r) * K + kc + c] = bf16_1(acs[r]);
    }
  }
}

extern "C" void kernel_launch(void* const* d_in, const int* in_sizes, int n_in,
                              void* d_out, int out_size, void* d_ws, size_t ws_size,
                              hipStream_t stream) {
  const float* u = (const float*)d_in[0];  // [B,N,K] f32
  const float* W = (const float*)d_in[1];  // [K,F] f32
  float* out = (float*)d_out;              // [B,O,D] f32

  char* ws = (char*)d_ws;
  unsigned short* Sp = (unsigned short*)ws;            // B*NT*O*K u16 (33.5MB)
  float* t = (float*)(Sp + (size_t)B * NT * O * K);    // B*O*K f32 (2MB)
  float* colsum = t + (size_t)B * O * K;               // B*K f32
  float* sumsq = colsum + (size_t)B * K;               // 16 (2 used)

  hipMemsetAsync(colsum, 0, ((size_t)B * K + 16) * sizeof(float), stream);

  k_colsum<<<dim3(B, 32), 256, 0, stream>>>(u, colsum);
  k_vjt<<<B * O, 512, 0, stream>>>(Sp, colsum, W, sumsq, 0, t);   // iter0 (uniform)
  k_route<<<dim3(B, NT), 256, 0, stream>>>(t, u, sumsq, 0, Sp);
  k_vjt<<<B * O, 512, 0, stream>>>(Sp, colsum, W, sumsq, 1, t);   // iter1
  k_route<<<dim3(B, NT), 256, 0, stream>>>(t, u, sumsq, 1, Sp);
  k_out<<<B * O, 512, 0, stream>>>(Sp, W, out);                   // iter2 + squash
}

// Round 12
// 190.329 us; speedup vs baseline: 1.3282x; 1.0584x over previous
//
#include <hip/hip_runtime.h>
#include <hip/hip_bf16.h>

// Capsule routing; u_hat never materialized. Per iter:
//   vjt: vj = S@W_o -> ssq_part (plain store); t = W_o@vj as bf16 hi/lo
//   route: bb = (t.u^T)/nrm -> softmax_o -> Spart[nt] = Wv.u (MFMA bf16 hi/lo)
// R11 skeleton (measured best) + pre-formatted operands:
//   k_prep emits u_bf (bf16) + colsum slabs (no atomics, no memset);
//   k_vjt emits t as bf16 hi/lo (route staging = pure copy);
//   sumsq via 1024-entry slab, reduced inside k_route (no memset).

constexpr int B = 32, N = 1024, K = 512, O = 32, D = 64, F = 2048;
constexpr int NT = 32;   // n-tile -> 32 slabs per b
constexpr int ST = 72;   // LDS u16 row stride: 144B, 16B-aligned, b128-friendly

typedef __attribute__((ext_vector_type(8))) short bf16x8;
typedef __attribute__((ext_vector_type(4))) float f32x4;

__device__ inline unsigned int pk_hi(float x, float y) {
  union { __hip_bfloat162 h; unsigned int u; } c;
  c.h = __float22bfloat162_rn(float2{x, y});
  return c.u;
}
__device__ inline unsigned short bf16_1(float x) {
  return (unsigned short)(pk_hi(x, 0.f) & 0xffffu);
}
__device__ inline void split2(float x, unsigned short& h, unsigned short& l) {
  h = bf16_1(x);
  l = bf16_1(x - __uint_as_float((unsigned int)h << 16));
}
__device__ inline float bf2f(unsigned short h) {
  return __uint_as_float((unsigned int)h << 16);
}
__device__ inline int swz(int r) { return ((r >> 3) & 7) << 3; }

__device__ inline bf16x8 frag_row(const unsigned short* p, int r, int k0) {
  return *(const bf16x8*)&p[r * ST + (k0 ^ swz(r))];
}
__device__ inline bf16x8 frag_col(const unsigned short* p, int c, int n0) {
  bf16x8 f;
#pragma unroll
  for (int j = 0; j < 8; j++) {
    int n = n0 + j;
    f[j] = (short)p[n * ST + (c ^ swz(n))];
  }
  return f;
}

// ---- prep: stream u once -> colsum slabs (plain stores) + u_bf (bf16) ----
// grid (B, 32), 256 thr; block handles 32 n-rows.
__global__ __launch_bounds__(256) void k_prep(const float* __restrict__ u,
                                              float* __restrict__ cs_part,
                                              unsigned short* __restrict__ u_bf) {
  __shared__ float4 red[128];
  int b = blockIdx.x, ntile = blockIdx.y, n0 = ntile * 32;
  int tid = threadIdx.x;
  int kq = (tid & 127) * 4, ng = tid >> 7;
  const float* ub = u + ((size_t)b * N + n0 + ng * 16) * K + kq;
  unsigned short* ubf = u_bf + ((size_t)b * N + n0 + ng * 16) * K + kq;
  float4 a = {0.f, 0.f, 0.f, 0.f};
#pragma unroll
  for (int nn = 0; nn < 16; nn++) {
    float4 v = *(const float4*)&ub[(size_t)nn * K];
    a.x += v.x; a.y += v.y; a.z += v.z; a.w += v.w;
    uint2 p;
    p.x = pk_hi(v.x, v.y);
    p.y = pk_hi(v.z, v.w);
    *(uint2*)&ubf[(size_t)nn * K] = p;
  }
  if (ng) red[tid & 127] = a;
  __syncthreads();
  if (!ng) {
    float4 o = red[tid];
    float* cs = cs_part + ((size_t)b * 32 + ntile) * K + kq;
    cs[0] = (a.x + o.x) * (1.f / 32.f);
    cs[1] = (a.y + o.y) * (1.f / 32.f);
    cs[2] = (a.z + o.z) * (1.f / 32.f);
    cs[3] = (a.w + o.w) * (1.f / 32.f);
  }
}

// vj[d]=sum_k s[k]W[k,o*64+d] -> ssq_part[slot*1024+bo]; t = W_o@vj bf16 hi/lo.
// slot 0: s = sum of 32 colsum slabs; else sum of 32 bf16 partial-S slabs.
__global__ __launch_bounds__(512) void k_vjt(const unsigned short* __restrict__ Sp,
                                             const float* __restrict__ cs_part,
                                             const float* __restrict__ W,
                                             float* __restrict__ ssq_part, int slot,
                                             unsigned short* __restrict__ t_hi,
                                             unsigned short* __restrict__ t_lo) {
  __shared__ __align__(16) float s_s[K];
  __shared__ float red[7][D];
  __shared__ __align__(16) float vs[D];
  int bo = blockIdx.x, b = bo >> 5, o = bo & 31;
  int d = threadIdx.x & 63, ks = threadIdx.x >> 6;  // 8-way k split
  {
    int i = threadIdx.x;  // 512 threads, one k each
    float a = 0.f;
    if (slot == 0) {
      const float* base = cs_part + (size_t)b * 32 * K;
#pragma unroll
      for (int nt = 0; nt < 32; nt++) a += base[(size_t)nt * K + i];
    } else {
      const unsigned short* base = Sp + ((size_t)b * NT * O + o) * K;
#pragma unroll
      for (int nt = 0; nt < NT; nt++) a += bf2f(base[(size_t)nt * O * K + i]);
    }
    s_s[i] = a;
  }
  __syncthreads();
  float acc = 0.f;
  const float* Wc = W + (size_t)o * D + d;
  for (int k = ks * 64; k < ks * 64 + 64; k += 4) {
    acc += s_s[k] * Wc[(size_t)k * F] + s_s[k + 1] * Wc[(size_t)(k + 1) * F] +
           s_s[k + 2] * Wc[(size_t)(k + 2) * F] + s_s[k + 3] * Wc[(size_t)(k + 3) * F];
  }
  if (ks) red[ks - 1][d] = acc;
  __syncthreads();
  if (ks == 0) {
#pragma unroll
    for (int j = 0; j < 7; j++) acc += red[j][d];
    vs[d] = acc;
    float ss = acc * acc;
#pragma unroll
    for (int m = 32; m >= 1; m >>= 1) ss += __shfl_xor(ss, m, 64);
    if (d == 0) ssq_part[slot * 1024 + bo] = ss;
  }
  __syncthreads();
  {  // t phase: wave handles 64 rows, 8 lanes/row (coalesced W reads)
    int wave = threadIdx.x >> 6, lane = threadIdx.x & 63;
    int rr = lane >> 3, dc = lane & 7;
    float4 va = *(const float4*)&vs[dc * 8];
    float4 vb = *(const float4*)&vs[dc * 8 + 4];
#pragma unroll
    for (int i = 0; i < 8; i++) {
      int kk = wave * 64 + i * 8 + rr;
      const float* Wr = W + (size_t)kk * F + o * 64 + dc * 8;
      float4 wa = *(const float4*)Wr;
      float4 wb = *(const float4*)(Wr + 4);
      float p = wa.x * va.x + wa.y * va.y + wa.z * va.z + wa.w * va.w +
                wb.x * vb.x + wb.y * vb.y + wb.z * vb.z + wb.w * vb.w;
      p += __shfl_xor(p, 1, 64);
      p += __shfl_xor(p, 2, 64);
      p += __shfl_xor(p, 4, 64);
      if (dc == 0) {
        unsigned short h, l;
        split2(p, h, l);
        t_hi[(size_t)bo * K + kk] = h;
        t_lo[(size_t)bo * K + kk] = l;
      }
    }
  }
}

// Final: vj from summed bf16 slabs -> squash -> out
__global__ __launch_bounds__(512) void k_out(const unsigned short* __restrict__ Sp,
                                             const float* __restrict__ W,
                                             float* __restrict__ out) {
  __shared__ __align__(16) float s_s[K];
  __shared__ float red[7][D];
  int bo = blockIdx.x, b = bo >> 5, o = bo & 31;
  int d = threadIdx.x & 63, ks = threadIdx.x >> 6;
  {
    const unsigned short* base = Sp + ((size_t)b * NT * O + o) * K;
    int i = threadIdx.x;
    float a = 0.f;
#pragma unroll
    for (int nt = 0; nt < NT; nt++) a += bf2f(base[(size_t)nt * O * K + i]);
    s_s[i] = a;
  }
  __syncthreads();
  float acc = 0.f;
  const float* Wc = W + (size_t)o * D + d;
  for (int k = ks * 64; k < ks * 64 + 64; k += 4) {
    acc += s_s[k] * Wc[(size_t)k * F] + s_s[k + 1] * Wc[(size_t)(k + 1) * F] +
           s_s[k + 2] * Wc[(size_t)(k + 2) * F] + s_s[k + 3] * Wc[(size_t)(k + 3) * F];
  }
  if (ks) red[ks - 1][d] = acc;
  __syncthreads();
  if (ks == 0) {
#pragma unroll
    for (int j = 0; j < 7; j++) acc += red[j][d];
    float ss = acc * acc;
#pragma unroll
    for (int m = 32; m >= 1; m >>= 1) ss += __shfl_xor(ss, m, 64);
    float s = ss + 1e-7f;
    out[(size_t)bo * D + d] = (sqrtf(s) / (0.5f + s)) * acc;
  }
}

// Fused routing step, 32-n tile, 256 thr (4 waves), grid (B,32)=1024 blocks.
// Staging is pure u16 copy (u_bf, t_hi/t_lo pre-formatted). ssq reduced here.
__global__ __launch_bounds__(256, 4) void k_route(const unsigned short* __restrict__ t_hi_g,
                                                  const unsigned short* __restrict__ t_lo_g,
                                                  const unsigned short* __restrict__ u_bf,
                                                  const float* __restrict__ ssq_part,
                                                  int slot,
                                                  unsigned short* __restrict__ Sp) {
  __shared__ unsigned short u_hi[32 * ST];                   // 4608 B
  __shared__ unsigned short t_hi[32 * ST], t_lo[32 * ST];    // 2x4608 B
  __shared__ float wv[32 * 36];                              // 4608 B logits
  __shared__ float psum[8 * 36];                             // softmax partials
  __shared__ float mbuf[36];
  unsigned short* wvh = t_hi;  // alias: t dead after phase 1
  unsigned short* wvl = t_lo;

  const int b = blockIdx.x, n0 = blockIdx.y * 32;
  const int tid = threadIdx.x, lane = tid & 63, wave = tid >> 6;
  const int m = lane & 15, oct = lane >> 4;
  const unsigned short* ubf = u_bf + ((size_t)b * N + n0) * K;
  const unsigned short* thg = t_hi_g + (size_t)b * O * K;
  const unsigned short* tlg = t_lo_g + (size_t)b * O * K;

  // staging index: 256 threads = 32 rows x 8 col-groups of 8 u16 (one uint4)
  const int sr = tid >> 3, sc8 = (tid & 7) * 8;
  const int scs = sc8 ^ swz(sr);  // swizzled LDS col

  // ---- phase 1: bb[32o][32n] = t . u^T ----
  const int mo = wave & 1, nt = wave >> 1;  // o-half, n-half (16x16 tiles)
  f32x4 accb = {0.f, 0.f, 0.f, 0.f};
  for (int kc = 0; kc < K; kc += 64) {
    __syncthreads();
    {  // pure-copy staging: t hi/lo + u, 3 uint4 loads + 3 b128 LDS stores
      const size_t go = (size_t)sr * K + kc;
      *(uint4*)&t_hi[sr * ST + scs] = *(const uint4*)&thg[go + sc8];
      *(uint4*)&t_hi[sr * ST + (scs ^ 8) ] = *(const uint4*)&thg[go + (sc8 ^ 8)];
      *(uint4*)&t_lo[sr * ST + scs] = *(const uint4*)&tlg[go + sc8];
      *(uint4*)&t_lo[sr * ST + (scs ^ 8)] = *(const uint4*)&tlg[go + (sc8 ^ 8)];
      *(uint4*)&u_hi[sr * ST + scs] = *(const uint4*)&ubf[go + sc8];
      *(uint4*)&u_hi[sr * ST + (scs ^ 8)] = *(const uint4*)&ubf[go + (sc8 ^ 8)];
    }
    __syncthreads();
#pragma unroll
    for (int ks = 0; ks < 64; ks += 32) {
      bf16x8 ah = frag_row(t_hi, mo * 16 + m, ks + oct * 8);
      bf16x8 al = frag_row(t_lo, mo * 16 + m, ks + oct * 8);
      bf16x8 bh = frag_row(u_hi, nt * 16 + m, ks + oct * 8);
      accb = __builtin_amdgcn_mfma_f32_16x16x32_bf16(ah, bh, accb, 0, 0, 0);
      accb = __builtin_amdgcn_mfma_f32_16x16x32_bf16(al, bh, accb, 0, 0, 0);
    }
  }
  __syncthreads();
  // ---- global-norm reduction from ssq_part (1024 entries) ----
  {
    const float* sp = ssq_part + slot * 1024;
    float sa = 0.f;
#pragma unroll
    for (int j = 0; j < 4; j++) sa += sp[tid + j * 256];
    psum[tid & 255] = sa;  // psum has 288 slots, use first 256
    __syncthreads();
    if (tid < 64) {
      float s = psum[tid] + psum[tid + 64] + psum[tid + 128] + psum[tid + 192];
#pragma unroll
      for (int mm = 32; mm >= 1; mm >>= 1) s += __shfl_xor(s, mm, 64);
      if (tid == 0) mbuf[0] = rsqrtf(fmaxf(s, 1e-12f));
    }
    __syncthreads();
  }
  const float nrm_inv = mbuf[0];
  __syncthreads();
#pragma unroll
  for (int r = 0; r < 4; r++)  // D: col=m (n), row=oct*4+r (o)
    wv[(mo * 16 + oct * 4 + r) * 36 + nt * 16 + m] = accb[r] * nrm_inv;
  __syncthreads();

  // ---- softmax over o, parallel: n=tid&31, g=tid>>5 owns 4 o's ----
  {
    int n = tid & 31, g = tid >> 5;
    float m4 = -1e30f;
#pragma unroll
    for (int j = 0; j < 4; j++) m4 = fmaxf(m4, wv[(g * 4 + j) * 36 + n]);
    psum[g * 36 + n] = m4;
    __syncthreads();
    if (tid < 32) {
      float mx = psum[tid];
#pragma unroll
      for (int gg = 1; gg < 8; gg++) mx = fmaxf(mx, psum[gg * 36 + tid]);
      mbuf[tid] = mx;
    }
    __syncthreads();
    float mx = mbuf[n];
    float s4 = 0.f;
#pragma unroll
    for (int j = 0; j < 4; j++) {
      float e = __expf(wv[(g * 4 + j) * 36 + n] - mx);
      wv[(g * 4 + j) * 36 + n] = e;
      s4 += e;
    }
    psum[g * 36 + n] = s4;
    __syncthreads();
    if (tid < 32) {
      float s = 0.f;
#pragma unroll
      for (int gg = 0; gg < 8; gg++) s += psum[gg * 36 + tid];
      mbuf[tid] = 1.f / s;
    }
    __syncthreads();
    float inv = mbuf[n];
#pragma unroll
    for (int j = 0; j < 4; j++) {  // Wv -> bf16 hi/lo into dead t region
      unsigned short h, l;
      split2(wv[(g * 4 + j) * 36 + n] * inv, h, l);
      wvh[(g * 4 + j) * ST + n] = h;
      wvl[(g * 4 + j) * ST + n] = l;
    }
  }
  __syncthreads();

  // ---- phase 2: Spart = Wv . u  (kred = n = 32, bf16 stores, no atomics) ----
  const int mo2 = wave & 1, kp = wave >> 1;  // o-half, ktile-pair
  const int o0 = mo2 * 16;
  bf16x8 a_h = *(const bf16x8*)&wvh[(o0 + m) * ST + oct * 8];
  bf16x8 a_l = *(const bf16x8*)&wvl[(o0 + m) * ST + oct * 8];
  unsigned short* Sb = Sp + ((size_t)b * NT + blockIdx.y) * O * K;
  for (int kc = 0; kc < K; kc += 64) {
    __syncthreads();
    {  // restage u chunk (pure copy)
      const size_t go = (size_t)sr * K + kc;
      *(uint4*)&u_hi[sr * ST + scs] = *(const uint4*)&ubf[go + sc8];
      *(uint4*)&u_hi[sr * ST + (scs ^ 8)] = *(const uint4*)&ubf[go + (sc8 ^ 8)];
    }
    __syncthreads();
#pragma unroll
    for (int kt = kp * 2; kt < kp * 2 + 2; kt++) {
      int c = kt * 16 + m;  // column within chunk
      bf16x8 bh = frag_col(u_hi, c, oct * 8);
      f32x4 acs = {0.f, 0.f, 0.f, 0.f};
      acs = __builtin_amdgcn_mfma_f32_16x16x32_bf16(a_h, bh, acs, 0, 0, 0);
      acs = __builtin_amdgcn_mfma_f32_16x16x32_bf16(a_l, bh, acs, 0, 0, 0);
#pragma unroll
      for (int r = 0; r < 4; r++)  // D: col=m -> kcol, row=oct*4+r -> o
        Sb[(size_t)(o0 + oct * 4 + r) * K + kc + c] = bf16_1(acs[r]);
    }
  }
}

extern "C" void kernel_launch(void* const* d_in, const int* in_sizes, int n_in,
                              void* d_out, int out_size, void* d_ws, size_t ws_size,
                              hipStream_t stream) {
  const float* u = (const float*)d_in[0];  // [B,N,K] f32
  const float* W = (const float*)d_in[1];  // [K,F] f32
  float* out = (float*)d_out;              // [B,O,D] f32

  char* ws = (char*)d_ws;
  unsigned short* Sp = (unsigned short*)ws;              // B*NT*O*K u16 (33.5MB)
  unsigned short* u_bf = Sp + (size_t)B * NT * O * K;    // B*N*K u16 (33.5MB)
  unsigned short* t_hi = u_bf + (size_t)B * N * K;       // B*O*K u16 (1MB)
  unsigned short* t_lo = t_hi + (size_t)B * O * K;       // B*O*K u16
  float* cs_part = (float*)(t_lo + (size_t)B * O * K);   // B*32*K f32 (2MB)
  float* ssq_part = cs_part + (size_t)B * 32 * K;        // 2048 f32

  k_prep<<<dim3(B, 32), 256, 0, stream>>>(u, cs_part, u_bf);
  k_vjt<<<B * O, 512, 0, stream>>>(Sp, cs_part, W, ssq_part, 0, t_hi, t_lo);
  k_route<<<dim3(B, NT), 256, 0, stream>>>(t_hi, t_lo, u_bf, ssq_part, 0, Sp);
  k_vjt<<<B * O, 512, 0, stream>>>(Sp, cs_part, W, ssq_part, 1, t_hi, t_lo);
  k_route<<<dim3(B, NT), 256, 0, stream>>>(t_hi, t_lo, u_bf, ssq_part, 1, Sp);
  k_out<<<B * O, 512, 0, stream>>>(Sp, W, out);
}